// Round 7
// baseline (599.589 us; speedup 1.0000x reference)
//
#include <hip/hip_runtime.h>
#include <hip/hip_bf16.h>

#define S_ 1024
#define P_ 1024
#define B_ 4
#define E_ 1024
#define J_ 2048
#define H_ 16
#define I_ 64

typedef __bf16 bf16_t;
typedef __bf16 bf16x8 __attribute__((ext_vector_type(8)));
typedef __bf16 bf16x4 __attribute__((ext_vector_type(4)));
typedef unsigned short u16x8 __attribute__((ext_vector_type(8)));
typedef float f32x4 __attribute__((ext_vector_type(4)));

#define MFMA16(a, b, c) __builtin_amdgcn_mfma_f32_16x16x32_bf16(a, b, c, 0, 0, 0)

// XOR-granule swizzle for stride-64 bf16 LDS tiles.
#define SWZ(r, c) (((r) << 6) + ((((((c) >> 3)) ^ ((r) & 7)) << 3)) + ((c) & 7))

typedef const __attribute__((address_space(1))) void* gp1_t;
typedef __attribute__((address_space(3))) void* lp3_t;
#define GLOAD16(g, l) __builtin_amdgcn_global_load_lds((gp1_t)(g), (lp3_t)(l), 16, 0, 0)

// ---------------- fp32 -> bf16 convert ----------------
__global__ __launch_bounds__(256) void cvt_kernel(const float* __restrict__ src,
                                                  bf16_t* __restrict__ dst, int n) {
    int i = (blockIdx.x * 256 + threadIdx.x) * 4;
    if (i < n) {
        float4 v = *(const float4*)(src + i);
        bf16x4 o = {(bf16_t)v.x, (bf16_t)v.y, (bf16_t)v.z, (bf16_t)v.w};
        *(bf16x4*)(dst + i) = o;
    }
}

// ---------------- W (K x N) fp32 -> W^T (N x K) bf16 ----------------
__global__ void transpose_cvt(const float* __restrict__ W, bf16_t* __restrict__ Wt,
                              int K, int N) {
    __shared__ float tile[32][33];
    int n0 = blockIdx.x * 32, k0 = blockIdx.y * 32;
    int x = threadIdx.x, y = threadIdx.y;
    for (int i = 0; i < 32; i += 8)
        tile[y + i][x] = W[(size_t)(k0 + y + i) * N + n0 + x];
    __syncthreads();
    for (int i = 0; i < 32; i += 8)
        Wt[(size_t)(n0 + y + i) * K + k0 + x] = (bf16_t)tile[x][y + i];
}

// ---------------- bf16 MFMA GEMM (global_load_lds staging, swizzled) ----------------
template <int EPI>
__global__ __launch_bounds__(256) void gemm_bf16(
    const bf16_t* __restrict__ A, const bf16_t* __restrict__ Bt,
    int M, int N, int K,
    bf16_t* __restrict__ out0, bf16_t* __restrict__ out1,
    const float* __restrict__ add0, const float* __restrict__ add1,
    float* __restrict__ outf) {
    __shared__ __attribute__((aligned(16))) bf16_t Al[128 * 64];
    __shared__ __attribute__((aligned(16))) bf16_t Bl[128 * 64];
    int tid = threadIdx.x;
    int wave = tid >> 6, lane = tid & 63, quad = lane >> 4, l16 = lane & 15;
    int m0 = blockIdx.y * 128, n0 = blockIdx.x * 128;
    int wm = (wave & 1) * 64, wn = (wave >> 1) * 64;

    int lrow = lane >> 3;
    int lgr = (lane & 7) ^ (lrow & 7);
    const bf16_t* gsrc = (wave < 2)
        ? A + (size_t)(m0 + (wave & 1) * 64 + lrow) * K + lgr * 8
        : Bt + (size_t)(n0 + (wave & 1) * 64 + lrow) * K + lgr * 8;
    bf16_t* lds_wave = ((wave < 2) ? Al : Bl) + (wave & 1) * 4096;

    f32x4 zero = {0.f, 0.f, 0.f, 0.f};
    f32x4 acc[4][4];
    #pragma unroll
    for (int i = 0; i < 4; i++)
        #pragma unroll
        for (int j = 0; j < 4; j++) acc[i][j] = zero;

    for (int k0 = 0; k0 < K; k0 += 64) {
        __syncthreads();
        #pragma unroll
        for (int q = 0; q < 8; q++)
            GLOAD16(gsrc + (size_t)(q * 8) * K + k0, lds_wave + q * 512);
        __syncthreads();
        #pragma unroll
        for (int ks = 0; ks < 2; ks++) {
            bf16x8 af[4], bfr[4];
            #pragma unroll
            for (int i = 0; i < 4; i++)
                af[i] = *(const bf16x8*)&Al[SWZ(wm + i * 16 + l16, ks * 32 + quad * 8)];
            #pragma unroll
            for (int j = 0; j < 4; j++)
                bfr[j] = *(const bf16x8*)&Bl[SWZ(wn + j * 16 + l16, ks * 32 + quad * 8)];
            #pragma unroll
            for (int i = 0; i < 4; i++)
                #pragma unroll
                for (int j = 0; j < 4; j++) acc[i][j] = MFMA16(af[i], bfr[j], acc[i][j]);
        }
    }
    #pragma unroll
    for (int i = 0; i < 4; i++)
        #pragma unroll
        for (int j = 0; j < 4; j++)
            #pragma unroll
            for (int reg = 0; reg < 4; reg++) {
                int m = m0 + wm + i * 16 + quad * 4 + reg;
                int n = n0 + wn + j * 16 + l16;
                float v = acc[i][j][reg];
                if (EPI == 0) {
                    out0[(size_t)m * N + n] = (bf16_t)v;
                } else if (EPI == 1) {
                    out0[(size_t)m * N + n] = (bf16_t)(v + add0[n]);
                    out1[(size_t)m * N + n] = (bf16_t)(v + add1[n]);
                } else {
                    outf[(size_t)m * N + n] = v + add0[(size_t)m * N + n];
                }
            }
}

// ---------------- flash attention: 128 s-rows/block, 2 row-groups/wave ----------------
// grid (8, B*H). K/V/P staged in LDS (shared by all waves/groups), register
// prefetch pipeline, P = 256-row ring (window span 192). Fixed-max softmax,
// direct awv store (no split-j, no atomics).
__global__ __launch_bounds__(256, 2) void flash_kernel(
    const bf16_t* __restrict__ qu, const bf16_t* __restrict__ qv,
    const bf16_t* __restrict__ kv, const bf16_t* __restrict__ pm,
    bf16_t* __restrict__ awv) {
    __shared__ __attribute__((aligned(16))) bf16_t Klds[64 * 64];     // 8 KB
    __shared__ __attribute__((aligned(16))) bf16_t Vt[64 * 64];       // 8 KB
    __shared__ __attribute__((aligned(16))) bf16_t Plds[256 * 64];    // 32 KB ring
    __shared__ __attribute__((aligned(16))) bf16_t Prob[4 * 16 * 64]; // 8 KB
    // 56 KB -> 2 blocks/CU; 512 blocks fully resident

    int tid = threadIdx.x;
    int wave = tid >> 6, lane = tid & 63, quad = lane >> 4, l16 = lane & 15;
    int s_blk = blockIdx.x;
    int s0 = s_blk * 128;
    int bh = blockIdx.y;
    int b = bh >> 4, h = bh & 15;
    int nt = 18 + 2 * s_blk;                    // (P + s0 + 128)/64

    // two row-groups per wave: local starts rg0, rg0+16
    int rg0 = wave * 32;
    int sg0 = s0 + rg0, sg1 = sg0 + 16;

    const bf16_t* qb0u = qu + ((size_t)(sg0 + l16) * B_ + b) * 1024 + h * 64 + quad * 8;
    const bf16_t* qb0v = qv + ((size_t)(sg0 + l16) * B_ + b) * 1024 + h * 64 + quad * 8;
    const bf16_t* qb1u = qu + ((size_t)(sg1 + l16) * B_ + b) * 1024 + h * 64 + quad * 8;
    const bf16_t* qb1v = qv + ((size_t)(sg1 + l16) * B_ + b) * 1024 + h * 64 + quad * 8;
    bf16x8 aqu0[2] = {*(const bf16x8*)(qb0u), *(const bf16x8*)(qb0u + 32)};
    bf16x8 aqv0[2] = {*(const bf16x8*)(qb0v), *(const bf16x8*)(qb0v + 32)};
    bf16x8 aqu1[2] = {*(const bf16x8*)(qb1u), *(const bf16x8*)(qb1u + 32)};
    bf16x8 aqv1[2] = {*(const bf16x8*)(qb1v), *(const bf16x8*)(qb1v + 32)};

    f32x4 zero = {0.f, 0.f, 0.f, 0.f};
    f32x4 accO0[4], accO1[4];
    #pragma unroll
    for (int ot = 0; ot < 4; ot++) { accO0[ot] = zero; accO1[ot] = zero; }
    float lrow0[4] = {0.f, 0.f, 0.f, 0.f};
    float lrow1[4] = {0.f, 0.f, 0.f, 0.f};

    const int w0 = 896 - s0;                    // ring base row (logical = w0 + j0 + o)
    const int woff1 = 96 - rg0;                 // group1 fragment base offset (o)
    const float SCL = 0.125f * 1.44269504088896f;

    int jr = tid >> 3, seg8g = tid & 7;         // K staging
    int jp = tid & 31, iseg = tid >> 5;         // V staging
    int pra = tid >> 3, pga = tid & 7;          // P staging (rows pra, pra+32)
    uint* VtU = (uint*)&Vt[0];
    bf16_t* ProbW = Prob + (wave << 10);

    // ---- prologue: stage K(0), V(0), P rows w0 .. w0+191 ----
    {
        const bf16_t* kp = kv + ((size_t)jr * B_ + b) * 2048 + h * 64 + seg8g * 8;
        uint4 ka = *(const uint4*)kp;
        uint4 kb = *(const uint4*)(kp + (size_t)32 * B_ * 2048);
        const bf16_t* vp = kv + ((size_t)(jp * 2) * B_ + b) * 2048 + 1024 + h * 64 + iseg * 8;
        u16x8 va = *(const u16x8*)vp;
        u16x8 vb = *(const u16x8*)(vp + (size_t)B_ * 2048);
        uint4 pd[6];
        #pragma unroll
        for (int r = 0; r < 6; r++) {
            int idx = tid + 256 * r;
            int pr = idx >> 3, pg = idx & 7;
            pd[r] = *(const uint4*)(pm + (size_t)(w0 + pr) * 1024 + h * 64 + pg * 8);
        }
        *(uint4*)&Klds[SWZ(jr, seg8g * 8)] = ka;
        *(uint4*)&Klds[SWZ(jr + 32, seg8g * 8)] = kb;
        #pragma unroll
        for (int e = 0; e < 8; e++) {
            int row = iseg * 8 + e;
            VtU[(row << 5) + ((((jp >> 2) ^ (row & 7)) << 2)) + (jp & 3)] =
                (uint)va[e] | ((uint)vb[e] << 16);
        }
        int base0 = (w0 >> 6) & 3;
        #pragma unroll
        for (int r = 0; r < 6; r++) {
            int idx = tid + 256 * r;
            int pr = idx >> 3, pg = idx & 7;
            int phys = base0 * 64 + pr; if (phys >= 256) phys -= 256;
            *(uint4*)&Plds[SWZ(phys, pg * 8)] = pd[r];
        }
    }
    __syncthreads();

    for (int it = 0; it < nt; it++) {
        int j0 = it * 64;
        bool pf = (it + 1 < nt);
        int base = ((w0 + j0) >> 6) & 3;

        // ---- register prefetch of tile it+1 ----
        uint4 ka, kb, pd0, pd1;
        u16x8 va, vb;
        if (pf) {
            int j1 = j0 + 64;
            const bf16_t* kp = kv + ((size_t)(j1 + jr) * B_ + b) * 2048 + h * 64 + seg8g * 8;
            ka = *(const uint4*)kp;
            kb = *(const uint4*)(kp + (size_t)32 * B_ * 2048);
            const bf16_t* vp = kv + ((size_t)(j1 + jp * 2) * B_ + b) * 2048 + 1024 + h * 64 + iseg * 8;
            va = *(const u16x8*)vp;
            vb = *(const u16x8*)(vp + (size_t)B_ * 2048);
            int lr0 = w0 + j0 + 192 + pra;      if (lr0 > J_ - 1) lr0 = J_ - 1;
            int lr1 = w0 + j0 + 224 + pra;      if (lr1 > J_ - 1) lr1 = J_ - 1;
            pd0 = *(const uint4*)(pm + (size_t)lr0 * 1024 + h * 64 + pga * 8);
            pd1 = *(const uint4*)(pm + (size_t)lr1 * 1024 + h * 64 + pga * 8);
        }

        // ---- shared K fragments ----
        bf16x8 bk[2][4];
        #pragma unroll
        for (int ks = 0; ks < 2; ks++)
            #pragma unroll
            for (int t = 0; t < 4; t++)
                bk[ks][t] = *(const bf16x8*)&Klds[SWZ(t * 16 + l16, ks * 32 + quad * 8)];
        // ---- shared V fragments ----
        bf16x8 bv[2][4];
        #pragma unroll
        for (int ks = 0; ks < 2; ks++)
            #pragma unroll
            for (int ot = 0; ot < 4; ot++)
                bv[ks][ot] = *(const bf16x8*)&Vt[SWZ(ot * 16 + l16, ks * 32 + quad * 8)];
        // ---- shared P fragments: 6-wide union, group1 uses 0..4, group0 uses 1..5 ----
        bf16x8 bp[2][6];
        #pragma unroll
        for (int ks = 0; ks < 2; ks++)
            #pragma unroll
            for (int t = 0; t < 6; t++) {
                int o = woff1 + t * 16 + l16;
                int phys = base * 64 + o; if (phys >= 256) phys -= 256;
                bp[ks][t] = *(const bf16x8*)&Plds[SWZ(phys, ks * 32 + quad * 8)];
            }

        // ================= group 0 =================
        {
            f32x4 cs[4], ep[5];
            #pragma unroll
            for (int t = 0; t < 4; t++) cs[t] = zero;
            #pragma unroll
            for (int t = 0; t < 5; t++) ep[t] = zero;
            #pragma unroll
            for (int ks = 0; ks < 2; ks++) {
                #pragma unroll
                for (int t = 0; t < 4; t++) cs[t] = MFMA16(aqu0[ks], bk[ks][t], cs[t]);
                #pragma unroll
                for (int t = 0; t < 5; t++) ep[t] = MFMA16(aqv0[ks], bp[ks][t + 1], ep[t]);
            }
            #pragma unroll
            for (int reg = 0; reg < 4; reg++) {
                int r = quad * 4 + reg;
                int s = sg0 + r;
                int idx = l16 + 15 - r;
                int srcl = quad * 16 + (idx & 15);
                float sh[5];
                #pragma unroll
                for (int t = 0; t < 5; t++) sh[t] = __shfl(ep[t][reg], srcl);
                float psum = 0.f;
                #pragma unroll
                for (int t = 0; t < 4; t++) {
                    float pos = (idx < 16) ? sh[t] : sh[t + 1];
                    float p = exp2f((cs[t][reg] + pos) * SCL);
                    p = (j0 + t * 16 + l16 > P_ + s) ? 0.f : p;
                    ProbW[SWZ(r, t * 16 + l16)] = (bf16_t)p;
                    psum += p;
                }
                lrow0[reg] += psum;
            }
            #pragma unroll
            for (int ks = 0; ks < 2; ks++) {
                bf16x8 pa = *(const bf16x8*)&ProbW[SWZ(l16, ks * 32 + quad * 8)];
                #pragma unroll
                for (int ot = 0; ot < 4; ot++) accO0[ot] = MFMA16(pa, bv[ks][ot], accO0[ot]);
            }
        }
        // ================= group 1 =================
        {
            f32x4 cs[4], ep[5];
            #pragma unroll
            for (int t = 0; t < 4; t++) cs[t] = zero;
            #pragma unroll
            for (int t = 0; t < 5; t++) ep[t] = zero;
            #pragma unroll
            for (int ks = 0; ks < 2; ks++) {
                #pragma unroll
                for (int t = 0; t < 4; t++) cs[t] = MFMA16(aqu1[ks], bk[ks][t], cs[t]);
                #pragma unroll
                for (int t = 0; t < 5; t++) ep[t] = MFMA16(aqv1[ks], bp[ks][t], ep[t]);
            }
            #pragma unroll
            for (int reg = 0; reg < 4; reg++) {
                int r = quad * 4 + reg;
                int s = sg1 + r;
                int idx = l16 + 15 - r;
                int srcl = quad * 16 + (idx & 15);
                float sh[5];
                #pragma unroll
                for (int t = 0; t < 5; t++) sh[t] = __shfl(ep[t][reg], srcl);
                float psum = 0.f;
                #pragma unroll
                for (int t = 0; t < 4; t++) {
                    float pos = (idx < 16) ? sh[t] : sh[t + 1];
                    float p = exp2f((cs[t][reg] + pos) * SCL);
                    p = (j0 + t * 16 + l16 > P_ + s) ? 0.f : p;
                    ProbW[SWZ(r, t * 16 + l16)] = (bf16_t)p;
                    psum += p;
                }
                lrow1[reg] += psum;
            }
            #pragma unroll
            for (int ks = 0; ks < 2; ks++) {
                bf16x8 pa = *(const bf16x8*)&ProbW[SWZ(l16, ks * 32 + quad * 8)];
                #pragma unroll
                for (int ot = 0; ot < 4; ot++) accO1[ot] = MFMA16(pa, bv[ks][ot], accO1[ot]);
            }
        }

        __syncthreads();
        if (pf) {
            *(uint4*)&Klds[SWZ(jr, seg8g * 8)] = ka;
            *(uint4*)&Klds[SWZ(jr + 32, seg8g * 8)] = kb;
            #pragma unroll
            for (int e2 = 0; e2 < 8; e2++) {
                int row = iseg * 8 + e2;
                VtU[(row << 5) + ((((jp >> 2) ^ (row & 7)) << 2)) + (jp & 3)] =
                    (uint)va[e2] | ((uint)vb[e2] << 16);
            }
            int slot = (base + 3) & 3;                     // rows w0+j0+192..+255
            *(uint4*)&Plds[SWZ(slot * 64 + pra, pga * 8)] = pd0;
            *(uint4*)&Plds[SWZ(slot * 64 + pra + 32, pga * 8)] = pd1;
        }
        __syncthreads();
    }

    // ---- epilogue: reduce row sums, normalize, store both groups ----
    #pragma unroll
    for (int reg = 0; reg < 4; reg++) {
        int r = quad * 4 + reg;
        float l0 = lrow0[reg], l1 = lrow1[reg];
        #pragma unroll
        for (int d = 1; d < 16; d <<= 1) { l0 += __shfl_xor(l0, d); l1 += __shfl_xor(l1, d); }
        float inv0 = 1.0f / l0, inv1 = 1.0f / l1;
        size_t ro0 = ((size_t)(sg0 + r) * B_ + b) * 1024 + h * 64;
        size_t ro1 = ((size_t)(sg1 + r) * B_ + b) * 1024 + h * 64;
        #pragma unroll
        for (int ot = 0; ot < 4; ot++) {
            awv[ro0 + ot * 16 + l16] = (bf16_t)(accO0[ot][reg] * inv0);
            awv[ro1 + ot * 16 + l16] = (bf16_t)(accO1[ot][reg] * inv1);
        }
    }
}

// ---------------- LayerNorm over E=1024 ----------------
__global__ __launch_bounds__(256) void ln_kernel(const float* __restrict__ x,
                                                 const float* __restrict__ gamma,
                                                 const float* __restrict__ beta,
                                                 float* __restrict__ out) {
    int row = blockIdx.x, tid = threadIdx.x;
    int lane = tid & 63, wave = tid >> 6;
    float4 v = ((const float4*)(x + (size_t)row * 1024))[tid];
    float s = v.x + v.y + v.z + v.w;
    float ss = v.x * v.x + v.y * v.y + v.z * v.z + v.w * v.w;
    #pragma unroll
    for (int sh = 1; sh < 64; sh <<= 1) { s += __shfl_xor(s, sh); ss += __shfl_xor(ss, sh); }
    __shared__ float red[8];
    if (lane == 0) { red[wave] = s; red[4 + wave] = ss; }
    __syncthreads();
    s = red[0] + red[1] + red[2] + red[3];
    ss = red[4] + red[5] + red[6] + red[7];
    float mean = s * (1.f / 1024.f);
    float var = ss * (1.f / 1024.f) - mean * mean;
    float inv = rsqrtf(var + 1e-5f);
    float4 g = ((const float4*)gamma)[tid];
    float4 bt = ((const float4*)beta)[tid];
    float4 o;
    o.x = (v.x - mean) * inv * g.x + bt.x;
    o.y = (v.y - mean) * inv * g.y + bt.y;
    o.z = (v.z - mean) * inv * g.z + bt.z;
    o.w = (v.w - mean) * inv * g.w + bt.w;
    ((float4*)(out + (size_t)row * 1024))[tid] = o;
}

extern "C" void kernel_launch(void* const* d_in, const int* in_sizes, int n_in,
                              void* d_out, int out_size, void* d_ws, size_t ws_size,
                              hipStream_t stream) {
    const float* inputMHA = (const float*)d_in[0];
    const float* posEmb   = (const float*)d_in[1];
    const float* memory   = (const float*)d_in[2];
    const float* u        = (const float*)d_in[3];
    const float* v        = (const float*)d_in[4];
    const float* W_kv     = (const float*)d_in[6];
    const float* W_q      = (const float*)d_in[7];
    const float* W_p      = (const float*)d_in[8];
    const float* W_o      = (const float*)d_in[9];
    const float* gamma    = (const float*)d_in[10];
    const float* beta     = (const float*)d_in[11];
    float* out = (float*)d_out;

    char* ws = (char*)d_ws;
    size_t off = 0;
    auto alloc = [&](size_t bytes) -> void* {
        void* p = ws + off;
        off += (bytes + 255) & ~(size_t)255;
        return p;
    };
    bf16_t* Xbf  = (bf16_t*)alloc((size_t)J_ * B_ * E_ * 2);
    bf16_t* Wkvt = (bf16_t*)alloc((size_t)2048 * 1024 * 2);
    bf16_t* Wqt  = (bf16_t*)alloc((size_t)1024 * 1024 * 2);
    bf16_t* Wpt  = (bf16_t*)alloc((size_t)1024 * 1024 * 2);
    bf16_t* Wot  = (bf16_t*)alloc((size_t)1024 * 1024 * 2);
    bf16_t* Pemb = (bf16_t*)alloc((size_t)2048 * 1024 * 2);
    bf16_t* kvb  = (bf16_t*)alloc((size_t)8192 * 2048 * 2);
    bf16_t* qub  = (bf16_t*)alloc((size_t)4096 * 1024 * 2);
    bf16_t* qvb  = (bf16_t*)alloc((size_t)4096 * 1024 * 2);
    bf16_t* pb   = (bf16_t*)alloc((size_t)2048 * 1024 * 2);
    bf16_t* awvb = (bf16_t*)alloc((size_t)4096 * 1024 * 2);
    float*  opre = (float*)alloc((size_t)4096 * 1024 * 4);

    cvt_kernel<<<P_ * B_ * E_ / 1024, 256, 0, stream>>>(memory, Xbf, P_ * B_ * E_);
    cvt_kernel<<<S_ * B_ * E_ / 1024, 256, 0, stream>>>(inputMHA, Xbf + (size_t)P_ * B_ * E_,
                                                        S_ * B_ * E_);
    cvt_kernel<<<J_ * E_ / 1024, 256, 0, stream>>>(posEmb, Pemb, J_ * E_);
    transpose_cvt<<<dim3(2048 / 32, 1024 / 32), dim3(32, 8), 0, stream>>>(W_kv, Wkvt, 1024, 2048);
    transpose_cvt<<<dim3(1024 / 32, 1024 / 32), dim3(32, 8), 0, stream>>>(W_q, Wqt, 1024, 1024);
    transpose_cvt<<<dim3(1024 / 32, 1024 / 32), dim3(32, 8), 0, stream>>>(W_p, Wpt, 1024, 1024);
    transpose_cvt<<<dim3(1024 / 32, 1024 / 32), dim3(32, 8), 0, stream>>>(W_o, Wot, 1024, 1024);

    gemm_bf16<0><<<dim3(2048 / 128, 8192 / 128), 256, 0, stream>>>(
        Xbf, Wkvt, 8192, 2048, 1024, kvb, nullptr, nullptr, nullptr, nullptr);
    gemm_bf16<1><<<dim3(1024 / 128, 4096 / 128), 256, 0, stream>>>(
        Xbf + (size_t)P_ * B_ * E_, Wqt, 4096, 1024, 1024, qub, qvb, u, v, nullptr);
    gemm_bf16<0><<<dim3(1024 / 128, 2048 / 128), 256, 0, stream>>>(
        Pemb, Wpt, 2048, 1024, 1024, pb, nullptr, nullptr, nullptr, nullptr);

    flash_kernel<<<dim3(8, B_ * H_), 256, 0, stream>>>(qub, qvb, kvb, pb, awvb);

    gemm_bf16<2><<<dim3(1024 / 128, 4096 / 128), 256, 0, stream>>>(
        awvb, Wot, 4096, 1024, 1024, nullptr, nullptr, inputMHA, nullptr, opre);
    ln_kernel<<<S_ * B_, 256, 0, stream>>>(opre, gamma, beta, out);
}

// Round 8
// 444.125 us; speedup vs baseline: 1.3500x; 1.3500x over previous
//
#include <hip/hip_runtime.h>
#include <hip/hip_bf16.h>

#define S_ 1024
#define P_ 1024
#define B_ 4
#define E_ 1024
#define J_ 2048
#define H_ 16
#define I_ 64

typedef __bf16 bf16_t;
typedef __bf16 bf16x8 __attribute__((ext_vector_type(8)));
typedef __bf16 bf16x4 __attribute__((ext_vector_type(4)));
typedef unsigned short u16x8 __attribute__((ext_vector_type(8)));
typedef float f32x4 __attribute__((ext_vector_type(4)));

#define MFMA16(a, b, c) __builtin_amdgcn_mfma_f32_16x16x32_bf16(a, b, c, 0, 0, 0)

// XOR-granule swizzle for stride-64 bf16 LDS tiles (flash only).
#define SWZ(r, c) (((r) << 6) + ((((((c) >> 3)) ^ ((r) & 7)) << 3)) + ((c) & 7))

// ---------------- fused fp32 -> bf16 converts (memory, inputMHA, posEmb) ----------------
__global__ __launch_bounds__(256) void cvt_all_kernel(const float* __restrict__ memory,
                                                      const float* __restrict__ input,
                                                      const float* __restrict__ posEmb,
                                                      bf16_t* __restrict__ Xbf,
                                                      bf16_t* __restrict__ Pemb) {
    // segments: [0,4096) memory->Xbf, [4096,8192) input->Xbf+P*B*E, [8192,10240) posEmb->Pemb
    int blk = blockIdx.x;
    const float* src;
    bf16_t* dst;
    if (blk < 4096) { src = memory; dst = Xbf; }
    else if (blk < 8192) { blk -= 4096; src = input; dst = Xbf + (size_t)P_ * B_ * E_; }
    else { blk -= 8192; src = posEmb; dst = Pemb; }
    int i = (blk * 256 + threadIdx.x) * 4;
    float4 v = *(const float4*)(src + i);
    bf16x4 o = {(bf16_t)v.x, (bf16_t)v.y, (bf16_t)v.z, (bf16_t)v.w};
    *(bf16x4*)(dst + i) = o;
}

// ---------------- fused weight transposes: W (K x N) fp32 -> W^T (N x K) bf16 ----------------
__global__ void trans_all_kernel(const float* __restrict__ W_kv, bf16_t* __restrict__ Wkvt,
                                 const float* __restrict__ W_q, bf16_t* __restrict__ Wqt,
                                 const float* __restrict__ W_p, bf16_t* __restrict__ Wpt,
                                 const float* __restrict__ W_o, bf16_t* __restrict__ Wot) {
    __shared__ float tile[32][33];
    int z = blockIdx.z;
    const float* W = (z == 0) ? W_kv : (z == 1) ? W_q : (z == 2) ? W_p : W_o;
    bf16_t* Wt = (z == 0) ? Wkvt : (z == 1) ? Wqt : (z == 2) ? Wpt : Wot;
    int N = (z == 0) ? 2048 : 1024;
    if (blockIdx.x * 32 >= N) return;
    int n0 = blockIdx.x * 32, k0 = blockIdx.y * 32;
    int x = threadIdx.x, y = threadIdx.y;
    for (int i = 0; i < 32; i += 8)
        tile[y + i][x] = W[(size_t)(k0 + y + i) * N + n0 + x];
    __syncthreads();
    for (int i = 0; i < 32; i += 8)
        Wt[(size_t)(n0 + y + i) * 1024 + k0 + x] = (bf16_t)tile[x][y + i];  // K == 1024 always
}

// ---------------- bf16 MFMA GEMM tile body (R3 padded-LDS staging) ----------------
// C(M,N) tile at (m0,n0): A(MxK) @ Bt(NxK)^T, K = 1024. Runtime epilogue:
// epi 0: bf16 store out0. epi 1: out0=acc+add0[n], out1=acc+add1[n] (bf16).
// epi 2: fp32 outf = acc + add0[m*N+n].
__device__ __forceinline__ void gemm_tile(
    const bf16_t* __restrict__ A, const bf16_t* __restrict__ Bt, int N,
    int m0, int n0, int epi,
    bf16_t* __restrict__ out0, bf16_t* __restrict__ out1,
    const float* __restrict__ add0, const float* __restrict__ add1,
    float* __restrict__ outf,
    bf16_t (*Al)[72], bf16_t (*Bl)[72]) {
    const int K = 1024;
    int tid = threadIdx.x;
    int wave = tid >> 6, lane = tid & 63, quad = lane >> 4, l16 = lane & 15;
    int wm = (wave & 1) * 64, wn = (wave >> 1) * 64;
    f32x4 zero = {0.f, 0.f, 0.f, 0.f};
    f32x4 acc[4][4];
    #pragma unroll
    for (int i = 0; i < 4; i++)
        #pragma unroll
        for (int j = 0; j < 4; j++) acc[i][j] = zero;

    for (int k0 = 0; k0 < K; k0 += 64) {
        __syncthreads();
        #pragma unroll
        for (int r = 0; r < 4; r++) {
            int idx = tid + 256 * r;
            int row = idx >> 3, seg = (idx & 7) * 8;
            *(uint4*)&Al[row][seg] = *(const uint4*)&A[(size_t)(m0 + row) * K + k0 + seg];
            *(uint4*)&Bl[row][seg] = *(const uint4*)&Bt[(size_t)(n0 + row) * K + k0 + seg];
        }
        __syncthreads();
        #pragma unroll
        for (int ks = 0; ks < 2; ks++) {
            bf16x8 af[4], bfr[4];
            #pragma unroll
            for (int i = 0; i < 4; i++)
                af[i] = *(const bf16x8*)&Al[wm + i * 16 + l16][ks * 32 + quad * 8];
            #pragma unroll
            for (int j = 0; j < 4; j++)
                bfr[j] = *(const bf16x8*)&Bl[wn + j * 16 + l16][ks * 32 + quad * 8];
            #pragma unroll
            for (int i = 0; i < 4; i++)
                #pragma unroll
                for (int j = 0; j < 4; j++) acc[i][j] = MFMA16(af[i], bfr[j], acc[i][j]);
        }
    }
    #pragma unroll
    for (int i = 0; i < 4; i++)
        #pragma unroll
        for (int j = 0; j < 4; j++)
            #pragma unroll
            for (int reg = 0; reg < 4; reg++) {
                int m = m0 + wm + i * 16 + quad * 4 + reg;
                int n = n0 + wn + j * 16 + l16;
                float v = acc[i][j][reg];
                if (epi == 0) {
                    out0[(size_t)m * N + n] = (bf16_t)v;
                } else if (epi == 1) {
                    out0[(size_t)m * N + n] = (bf16_t)(v + add0[n]);
                    out1[(size_t)m * N + n] = (bf16_t)(v + add1[n]);
                } else {
                    outf[(size_t)m * N + n] = v + add0[(size_t)m * N + n];
                }
            }
}

// ---------------- packed pre-attention GEMMs: kv | q(+u,+v dual) | p ----------------
// grid.x = 1024 + 256 + 128 = 1408 blocks of 128x128.
__global__ __launch_bounds__(256) void gemm3_kernel(
    const bf16_t* __restrict__ Xbf, const bf16_t* __restrict__ Wkvt, bf16_t* __restrict__ kvb,
    const bf16_t* __restrict__ Wqt, bf16_t* __restrict__ qub, bf16_t* __restrict__ qvb,
    const float* __restrict__ u, const float* __restrict__ v,
    const bf16_t* __restrict__ Pemb, const bf16_t* __restrict__ Wpt, bf16_t* __restrict__ pb) {
    __shared__ __attribute__((aligned(16))) bf16_t Al[128][72];
    __shared__ __attribute__((aligned(16))) bf16_t Bl[128][72];
    int id = blockIdx.x;
    if (id < 1024) {
        gemm_tile(Xbf, Wkvt, 2048, (id >> 4) * 128, (id & 15) * 128, 0,
                  kvb, nullptr, nullptr, nullptr, nullptr, Al, Bl);
    } else if (id < 1280) {
        int t = id - 1024;
        gemm_tile(Xbf + (size_t)P_ * B_ * E_, Wqt, 1024, (t >> 3) * 128, (t & 7) * 128, 1,
                  qub, qvb, u, v, nullptr, Al, Bl);
    } else {
        int t = id - 1280;
        gemm_tile(Pemb, Wpt, 1024, (t >> 3) * 128, (t & 7) * 128, 0,
                  pb, nullptr, nullptr, nullptr, nullptr, Al, Bl);
    }
}

// ---------------- output GEMM: opre = awv @ W_o + inputMHA (fp32) ----------------
__global__ __launch_bounds__(256) void gemmo_kernel(
    const bf16_t* __restrict__ awvb, const bf16_t* __restrict__ Wot,
    const float* __restrict__ inputMHA, float* __restrict__ opre) {
    __shared__ __attribute__((aligned(16))) bf16_t Al[128][72];
    __shared__ __attribute__((aligned(16))) bf16_t Bl[128][72];
    int id = blockIdx.x;
    gemm_tile(awvb, Wot, 1024, (id >> 3) * 128, (id & 7) * 128, 2,
              nullptr, nullptr, inputMHA, nullptr, opre, Al, Bl);
}

// ---------------- flash attention (R4-proven): chunked split-j + atomic combine ----------------
__global__ __launch_bounds__(256) void flash_kernel(
    const bf16_t* __restrict__ qu, const bf16_t* __restrict__ qv,
    const bf16_t* __restrict__ kv, const bf16_t* __restrict__ pm,
    float* __restrict__ Oacc, float* __restrict__ lacc) {
    __shared__ __attribute__((aligned(16))) bf16_t Klds[64 * 64];
    __shared__ __attribute__((aligned(16))) bf16_t Vt[64 * 64];
    __shared__ __attribute__((aligned(16))) bf16_t Plds[128 * 64];   // ring
    __shared__ __attribute__((aligned(16))) bf16_t Prob[4 * 16 * 64];

    int tid = threadIdx.x;
    int wave = tid >> 6, lane = tid & 63, quad = lane >> 4, l16 = lane & 15;

    int x = blockIdx.x;
    int s_blk, c;
    if (x < 24) { s_blk = x / 3; c = x - s_blk * 3; }
    else        { int y = x - 24; s_blk = 8 + (y >> 2); c = y & 3; }
    int nt = 17 + s_blk;
    int t0 = c * 8;
    int t1 = t0 + 8; if (t1 > nt) t1 = nt;

    int s0 = s_blk * 64;
    int bh = blockIdx.y;
    int b = bh >> 4, h = bh & 15;
    int srow0 = s0 + wave * 16;

    const bf16_t* qub = qu + ((size_t)(srow0 + l16) * B_ + b) * 1024 + h * 64 + quad * 8;
    const bf16_t* qvb = qv + ((size_t)(srow0 + l16) * B_ + b) * 1024 + h * 64 + quad * 8;
    bf16x8 aqu0 = *(const bf16x8*)(qub);
    bf16x8 aqu1 = *(const bf16x8*)(qub + 32);
    bf16x8 aqv0 = *(const bf16x8*)(qvb);
    bf16x8 aqv1 = *(const bf16x8*)(qvb + 32);

    f32x4 zero = {0.f, 0.f, 0.f, 0.f};
    f32x4 accO[4];
    #pragma unroll
    for (int ot = 0; ot < 4; ot++) accO[ot] = zero;
    float lrowp[4] = {0.f, 0.f, 0.f, 0.f};

    const int w0u = 960 - s0;
    const int woff = 48 - wave * 16;
    const float SCL = 0.125f * 1.44269504088896f;

    int jr = tid >> 3, seg8g = tid & 7;
    int jp = tid & 31, iseg = tid >> 5;
    uint* VtU = (uint*)&Vt[0];
    bf16_t* ProbW = Prob + (wave << 10);

    {
        int j0 = t0 * 64;
        const bf16_t* kp = kv + ((size_t)(j0 + jr) * B_ + b) * 2048 + h * 64 + seg8g * 8;
        uint4 ka = *(const uint4*)kp;
        uint4 kb = *(const uint4*)(kp + (size_t)32 * B_ * 2048);
        const bf16_t* vp = kv + ((size_t)(j0 + jp * 2) * B_ + b) * 2048 + 1024 + h * 64 + iseg * 8;
        u16x8 va = *(const u16x8*)vp;
        u16x8 vb = *(const u16x8*)(vp + (size_t)B_ * 2048);
        uint4 pd[4];
        #pragma unroll
        for (int r = 0; r < 4; r++) {
            int idx = tid + 256 * r;
            int pr = idx >> 3, pg = idx & 7;
            int lr = w0u + j0 + pr; if (lr > J_ - 1) lr = J_ - 1;
            pd[r] = *(const uint4*)(pm + (size_t)lr * 1024 + h * 64 + pg * 8);
        }
        *(uint4*)&Klds[SWZ(jr, seg8g * 8)] = ka;
        *(uint4*)&Klds[SWZ(jr + 32, seg8g * 8)] = kb;
        #pragma unroll
        for (int e = 0; e < 8; e++) {
            int row = iseg * 8 + e;
            VtU[(row << 5) + ((((jp >> 2) ^ (row & 7)) << 2)) + (jp & 3)] =
                (uint)va[e] | ((uint)vb[e] << 16);
        }
        #pragma unroll
        for (int r = 0; r < 4; r++) {
            int idx = tid + 256 * r;
            int pr = idx >> 3, pg = idx & 7;
            *(uint4*)&Plds[SWZ((w0u + j0 + pr) & 127, pg * 8)] = pd[r];
        }
    }
    __syncthreads();

    for (int it = t0; it < t1; it++) {
        int j0 = it * 64;
        bool pf = (it + 1 < t1);
        uint4 ka, kb, pd0, pd1;
        u16x8 va, vb;
        int pr0 = tid >> 3, pg0 = tid & 7;
        int pr1 = (tid + 256) >> 3, pg1 = tid & 7;
        if (pf) {
            int j1 = j0 + 64;
            const bf16_t* kp = kv + ((size_t)(j1 + jr) * B_ + b) * 2048 + h * 64 + seg8g * 8;
            ka = *(const uint4*)kp;
            kb = *(const uint4*)(kp + (size_t)32 * B_ * 2048);
            const bf16_t* vp = kv + ((size_t)(j1 + jp * 2) * B_ + b) * 2048 + 1024 + h * 64 + iseg * 8;
            va = *(const u16x8*)vp;
            vb = *(const u16x8*)(vp + (size_t)B_ * 2048);
            int lr0 = w0u + j0 + 128 + pr0; if (lr0 > J_ - 1) lr0 = J_ - 1;
            int lr1 = w0u + j0 + 128 + pr1; if (lr1 > J_ - 1) lr1 = J_ - 1;
            pd0 = *(const uint4*)(pm + (size_t)lr0 * 1024 + h * 64 + pg0 * 8);
            pd1 = *(const uint4*)(pm + (size_t)lr1 * 1024 + h * 64 + pg1 * 8);
        }

        f32x4 cs[4];
        #pragma unroll
        for (int t = 0; t < 4; t++) cs[t] = zero;
        #pragma unroll
        for (int ks = 0; ks < 2; ks++) {
            bf16x8 aq = ks ? aqu1 : aqu0;
            #pragma unroll
            for (int t = 0; t < 4; t++) {
                bf16x8 bk = *(const bf16x8*)&Klds[SWZ(t * 16 + l16, ks * 32 + quad * 8)];
                cs[t] = MFMA16(aq, bk, cs[t]);
            }
        }
        f32x4 ep[5];
        #pragma unroll
        for (int t = 0; t < 5; t++) ep[t] = zero;
        #pragma unroll
        for (int ks = 0; ks < 2; ks++) {
            bf16x8 aq = ks ? aqv1 : aqv0;
            #pragma unroll
            for (int t = 0; t < 5; t++) {
                int prow = (w0u + j0 + woff + t * 16 + l16) & 127;
                bf16x8 bp = *(const bf16x8*)&Plds[SWZ(prow, ks * 32 + quad * 8)];
                ep[t] = MFMA16(aq, bp, ep[t]);
            }
        }

        #pragma unroll
        for (int reg = 0; reg < 4; reg++) {
            int r = quad * 4 + reg;
            int s = srow0 + r;
            int idx = l16 + 15 - r;
            int srcl = quad * 16 + (idx & 15);
            float sh[5];
            #pragma unroll
            for (int t = 0; t < 5; t++) sh[t] = __shfl(ep[t][reg], srcl);
            float psum = 0.f;
            #pragma unroll
            for (int t = 0; t < 4; t++) {
                float pos = (idx < 16) ? sh[t] : sh[t + 1];
                float p = exp2f((cs[t][reg] + pos) * SCL);
                p = (j0 + t * 16 + l16 > P_ + s) ? 0.f : p;
                ProbW[SWZ(r, t * 16 + l16)] = (bf16_t)p;
                psum += p;
            }
            lrowp[reg] += psum;
        }

        #pragma unroll
        for (int ks = 0; ks < 2; ks++) {
            bf16x8 pa = *(const bf16x8*)&Prob[(wave << 10) + SWZ(l16, ks * 32 + quad * 8)];
            #pragma unroll
            for (int ot = 0; ot < 4; ot++) {
                bf16x8 bv = *(const bf16x8*)&Vt[SWZ(ot * 16 + l16, ks * 32 + quad * 8)];
                accO[ot] = MFMA16(pa, bv, accO[ot]);
            }
        }

        __syncthreads();
        if (pf) {
            *(uint4*)&Klds[SWZ(jr, seg8g * 8)] = ka;
            *(uint4*)&Klds[SWZ(jr + 32, seg8g * 8)] = kb;
            #pragma unroll
            for (int e2 = 0; e2 < 8; e2++) {
                int row = iseg * 8 + e2;
                VtU[(row << 5) + ((((jp >> 2) ^ (row & 7)) << 2)) + (jp & 3)] =
                    (uint)va[e2] | ((uint)vb[e2] << 16);
            }
            *(uint4*)&Plds[SWZ((w0u + j0 + pr0) & 127, pg0 * 8)] = pd0;
            *(uint4*)&Plds[SWZ((w0u + j0 + pr1) & 127, pg1 * 8)] = pd1;
        }
        __syncthreads();
    }

    #pragma unroll
    for (int reg = 0; reg < 4; reg++) {
        int r = quad * 4 + reg;
        int srow = srow0 + r;
        float l = lrowp[reg];
        #pragma unroll
        for (int d = 1; d < 16; d <<= 1) l += __shfl_xor(l, d);
        if (l16 == 0) atomicAdd(&lacc[((size_t)srow * B_ + b) * H_ + h], l);
        size_t rowoff = ((size_t)srow * B_ + b) * 1024 + h * 64;
        #pragma unroll
        for (int ot = 0; ot < 4; ot++)
            atomicAdd(&Oacc[rowoff + ot * 16 + l16], accO[ot][reg]);
    }
}

// ---------------- combine/normalize: awv = Oacc / lacc ----------------
__global__ __launch_bounds__(256) void norm_kernel(const float* __restrict__ Oacc,
                                                   const float* __restrict__ lacc,
                                                   bf16_t* __restrict__ awv) {
    int i4 = (blockIdx.x * 256 + threadIdx.x) * 4;
    int row = i4 >> 6;
    float inv = 1.0f / lacc[row];
    float4 o = *(const float4*)(Oacc + i4);
    bf16x4 r = {(bf16_t)(o.x * inv), (bf16_t)(o.y * inv),
                (bf16_t)(o.z * inv), (bf16_t)(o.w * inv)};
    *(bf16x4*)(awv + i4) = r;
}

// ---------------- LayerNorm over E=1024 ----------------
__global__ __launch_bounds__(256) void ln_kernel(const float* __restrict__ x,
                                                 const float* __restrict__ gamma,
                                                 const float* __restrict__ beta,
                                                 float* __restrict__ out) {
    int row = blockIdx.x, tid = threadIdx.x;
    int lane = tid & 63, wave = tid >> 6;
    float4 v = ((const float4*)(x + (size_t)row * 1024))[tid];
    float s = v.x + v.y + v.z + v.w;
    float ss = v.x * v.x + v.y * v.y + v.z * v.z + v.w * v.w;
    #pragma unroll
    for (int sh = 1; sh < 64; sh <<= 1) { s += __shfl_xor(s, sh); ss += __shfl_xor(ss, sh); }
    __shared__ float red[8];
    if (lane == 0) { red[wave] = s; red[4 + wave] = ss; }
    __syncthreads();
    s = red[0] + red[1] + red[2] + red[3];
    ss = red[4] + red[5] + red[6] + red[7];
    float mean = s * (1.f / 1024.f);
    float var = ss * (1.f / 1024.f) - mean * mean;
    float inv = rsqrtf(var + 1e-5f);
    float4 g = ((const float4*)gamma)[tid];
    float4 bt = ((const float4*)beta)[tid];
    float4 o;
    o.x = (v.x - mean) * inv * g.x + bt.x;
    o.y = (v.y - mean) * inv * g.y + bt.y;
    o.z = (v.z - mean) * inv * g.z + bt.z;
    o.w = (v.w - mean) * inv * g.w + bt.w;
    ((float4*)(out + (size_t)row * 1024))[tid] = o;
}

extern "C" void kernel_launch(void* const* d_in, const int* in_sizes, int n_in,
                              void* d_out, int out_size, void* d_ws, size_t ws_size,
                              hipStream_t stream) {
    const float* inputMHA = (const float*)d_in[0];
    const float* posEmb   = (const float*)d_in[1];
    const float* memory   = (const float*)d_in[2];
    const float* u        = (const float*)d_in[3];
    const float* v        = (const float*)d_in[4];
    const float* W_kv     = (const float*)d_in[6];
    const float* W_q      = (const float*)d_in[7];
    const float* W_p      = (const float*)d_in[8];
    const float* W_o      = (const float*)d_in[9];
    const float* gamma    = (const float*)d_in[10];
    const float* beta     = (const float*)d_in[11];
    float* out = (float*)d_out;

    char* ws = (char*)d_ws;
    size_t off = 0;
    auto alloc = [&](size_t bytes) -> void* {
        void* p = ws + off;
        off += (bytes + 255) & ~(size_t)255;
        return p;
    };
    bf16_t* Xbf  = (bf16_t*)alloc((size_t)J_ * B_ * E_ * 2);
    bf16_t* Wkvt = (bf16_t*)alloc((size_t)2048 * 1024 * 2);
    bf16_t* Wqt  = (bf16_t*)alloc((size_t)1024 * 1024 * 2);
    bf16_t* Wpt  = (bf16_t*)alloc((size_t)1024 * 1024 * 2);
    bf16_t* Wot  = (bf16_t*)alloc((size_t)1024 * 1024 * 2);
    bf16_t* Pemb = (bf16_t*)alloc((size_t)2048 * 1024 * 2);
    bf16_t* kvb  = (bf16_t*)alloc((size_t)8192 * 2048 * 2);
    bf16_t* qub  = (bf16_t*)alloc((size_t)4096 * 1024 * 2);
    bf16_t* qvb  = (bf16_t*)alloc((size_t)4096 * 1024 * 2);
    bf16_t* pb   = (bf16_t*)alloc((size_t)2048 * 1024 * 2);
    bf16_t* awvb = (bf16_t*)alloc((size_t)4096 * 1024 * 2);
    float*  opre = (float*)alloc((size_t)4096 * 1024 * 4);
    float*  Oacc = (float*)alloc((size_t)4096 * 1024 * 4);
    float*  lacc = (float*)alloc((size_t)S_ * B_ * H_ * 4);

    hipMemsetAsync(Oacc, 0, (size_t)4096 * 1024 * 4, stream);
    hipMemsetAsync(lacc, 0, (size_t)S_ * B_ * H_ * 4, stream);

    cvt_all_kernel<<<10240, 256, 0, stream>>>(memory, inputMHA, posEmb, Xbf, Pemb);
    trans_all_kernel<<<dim3(64, 32, 4), dim3(32, 8), 0, stream>>>(
        W_kv, Wkvt, W_q, Wqt, W_p, Wpt, W_o, Wot);

    gemm3_kernel<<<1408, 256, 0, stream>>>(Xbf, Wkvt, kvb, Wqt, qub, qvb, u, v, Pemb, Wpt, pb);

    flash_kernel<<<dim3(56, B_ * H_), 256, 0, stream>>>(qub, qvb, kvb, pb, Oacc, lacc);
    norm_kernel<<<4096, 256, 0, stream>>>(Oacc, lacc, awvb);

    gemmo_kernel<<<256, 256, 0, stream>>>(awvb, Wot, inputMHA, opre);
    ln_kernel<<<S_ * B_, 256, 0, stream>>>(opre, gamma, beta, out);
}